// Round 4
// baseline (336.003 us; speedup 1.0000x reference)
//
#include <hip/hip_runtime.h>
#include <hip/hip_bf16.h>

typedef __attribute__((ext_vector_type(8)))  __bf16 bf16x8;
typedef __attribute__((ext_vector_type(4)))  float  f32x4;
typedef __attribute__((ext_vector_type(16))) float  f32x16;

#define N_   4096
#define CQD  128

static __device__ __forceinline__ unsigned short f2bf(float f) {
    union { float f; unsigned int u; } cv; cv.f = f;
    unsigned int u = cv.u;
    u += 0x7fffu + ((u >> 16) & 1u);   // RNE
    return (unsigned short)(u >> 16);
}
static __device__ __forceinline__ f32x4 mfma16(bf16x8 a, bf16x8 b, f32x4 c) {
    return __builtin_amdgcn_mfma_f32_16x16x32_bf16(a, b, c, 0, 0, 0);
}
static __device__ __forceinline__ f32x16 mfma32(bf16x8 a, bf16x8 b, f32x16 c) {
    return __builtin_amdgcn_mfma_f32_32x32x16_bf16(a, b, c, 0, 0, 0);
}

// ---------------------------------------------------------------------------
// proj: x2d (B,64,N*16) -> Qb[n][c'], Kb[m][c'] (c' contig), PV[c'][m] (m contig)
// grid 512 (2 b x 256 col-tiles of 256), block 256. Thread owns 1 column:
// xr[64] in VGPRs; W broadcast lane->all via v_readlane (NO memory in inner
// loop). 20 chunks of 4 output rows, W chunk loads software-pipelined.
// ---------------------------------------------------------------------------
__global__ __launch_bounds__(256) void proj_kernel(
    const float* __restrict__ x2d,
    const float* __restrict__ Wq, const float* __restrict__ bq,
    const float* __restrict__ Wk, const float* __restrict__ bk,
    const float* __restrict__ Wv, const float* __restrict__ bv,
    unsigned short* __restrict__ Qb, unsigned short* __restrict__ Kb,
    unsigned short* __restrict__ PV)
{
    const int t    = threadIdx.x;
    const int blk  = blockIdx.x;
    const int b    = blk >> 8;
    const int tile = blk & 255;
    const int col  = (tile << 8) + t;
    const int n    = col >> 4;
    const int dd   = col & 15;
    const int lane = t & 63;

    const float* xb = x2d + (size_t)b * 64 * 65536 + col;
    float xr[64];
#pragma unroll
    for (int c = 0; c < 64; ++c) xr[c] = xb[(size_t)c * 65536];

    unsigned short* qb  = Qb + (size_t)b * N_ * CQD + (size_t)n * CQD + dd;
    unsigned short* kb  = Kb + (size_t)b * N_ * CQD + (size_t)n * CQD + dd;
    unsigned short* pvb = PV + (size_t)b * 1024 * N_;

    auto wptr = [&](int jb) -> const float* {
        if (jb < 8)  return Wq + jb * 64;
        if (jb < 16) return Wk + (jb - 8) * 64;
        return Wv + (jb - 16) * 64;
    };
    auto bptr = [&](int jb) -> const float* {
        if (jb < 8)  return bq + jb;
        if (jb < 16) return bk + (jb - 8);
        return bv + (jb - 16);
    };

    float wc[4], wn[4];
    {
        const float* wp = wptr(0);
#pragma unroll
        for (int jj = 0; jj < 4; ++jj) wc[jj] = wp[jj * 64 + lane];
    }
    for (int jc = 0; jc < 20; ++jc) {
        const int jb = jc * 4;
        {
            const float* wp = wptr(jb + 4 < 80 ? jb + 4 : 0);
#pragma unroll
            for (int jj = 0; jj < 4; ++jj) wn[jj] = wp[jj * 64 + lane];
        }
        const float* bp = bptr(jb);
        float acc[4];
#pragma unroll
        for (int jj = 0; jj < 4; ++jj) acc[jj] = bp[jj];
#pragma unroll
        for (int c = 0; c < 64; ++c) {
#pragma unroll
            for (int jj = 0; jj < 4; ++jj) {
                const float wv_ = __int_as_float(
                    __builtin_amdgcn_readlane(__float_as_int(wc[jj]), c));
                acc[jj] += wv_ * xr[c];
            }
        }
        if (jb < 8) {
#pragma unroll
            for (int jj = 0; jj < 4; ++jj) qb[(jb + jj) * 16] = f2bf(acc[jj]);
        } else if (jb < 16) {
#pragma unroll
            for (int jj = 0; jj < 4; ++jj) kb[(jb - 8 + jj) * 16] = f2bf(acc[jj]);
        } else {
#pragma unroll
            for (int jj = 0; jj < 4; ++jj)
                pvb[(size_t)(((jb - 16 + jj) << 4) + dd) * N_ + n] = f2bf(acc[jj]);
        }
#pragma unroll
        for (int jj = 0; jj < 4; ++jj) wc[jj] = wn[jj];
    }
}

// ---------------------------------------------------------------------------
// attn v4: 256 blocks = (b2 x ch2) [2 XCDs each] x 64 n-tiles. 8 waves/512thr.
// Wave w: E' slice (msel=w&3 m-16, nh=w>>2 n-32, swapped mfma(K,Q)) and
// PV tile n64 x c64 (c base w*64 in the c-half) with 32x32x16 MFMA.
// Per 64-m iter: issue B-frags (this iter) + K-frags (next iter) FIRST, then
// E' from pre-loaded K (no waits), exp -> swizzled 8KB p_lds, ONE barrier
// (drains loads), then PV pure compute. Unnormalized acc + rowsum; divide
// + gamma*O + x3d epilogue.
// ---------------------------------------------------------------------------
__global__ __launch_bounds__(512, 2) void attn_kernel(
    const unsigned short* __restrict__ Qb, const unsigned short* __restrict__ Kb,
    const unsigned short* __restrict__ PV,
    const float* __restrict__ x3d, const float* __restrict__ gamma_p,
    float* __restrict__ outp)
{
    __shared__ __align__(16) unsigned char p_lds[2][8192];  // [64 rows][128B], XOR-swz
    __shared__ float red[64];

    const int t   = threadIdx.x;
    const int w   = t >> 6;
    const int l   = t & 63;
    const int lo  = l & 15;
    const int hi  = l >> 4;
    const int lo5 = l & 31;
    const int hi1 = l >> 5;

    const int id    = blockIdx.x;
    const int combo = id & 3;            // (b,ch) -> XCDs {combo, combo+4}
    const int ch    = combo & 1;
    const int b     = combo >> 1;
    const int ntile = id >> 2;
    const int n0    = ntile << 6;
    const int msel  = w & 3;
    const int nh    = w >> 2;
    const int cb    = (ch << 9) + (w << 6);   // wave's c' base (64-wide)

    const unsigned short* qp  = Qb + (size_t)b * N_ * CQD;
    const unsigned short* kp  = Kb + (size_t)b * N_ * CQD;
    const unsigned short* pvp = PV + (size_t)b * 1024 * N_;

    // Q B-frags for E' (n-cols of this wave's nh half), held all kernel
    bf16x8 qf[2][4];
#pragma unroll
    for (int nb = 0; nb < 2; ++nb)
#pragma unroll
        for (int kk = 0; kk < 4; ++kk)
            qf[nb][kk] = *reinterpret_cast<const bf16x8*>(
                qp + (size_t)(n0 + nh * 32 + nb * 16 + lo) * CQD + kk * 32 + hi * 8);

    // K A-frags for iter 0
    bf16x8 kc[4];
#pragma unroll
    for (int kk = 0; kk < 4; ++kk)
        kc[kk] = *reinterpret_cast<const bf16x8*>(
            kp + (size_t)(msel * 16 + lo) * CQD + kk * 32 + hi * 8);

    f32x16 acc[2][2];
#pragma unroll
    for (int i = 0; i < 2; ++i)
#pragma unroll
        for (int j = 0; j < 2; ++j)
#pragma unroll
            for (int r = 0; r < 16; ++r) acc[i][j][r] = 0.f;
    float rs[2] = {0.f, 0.f};

    if (t < 64) red[t] = 0.f;

    for (int it = 0; it < 64; ++it) {
        const int m0 = it << 6;

        // ---- issue loads first: PV B-frags (this iter), K (next iter) ----
        bf16x8 Bf[4][2];
#pragma unroll
        for (int ms = 0; ms < 4; ++ms)
#pragma unroll
            for (int cs = 0; cs < 2; ++cs)
                Bf[ms][cs] = *reinterpret_cast<const bf16x8*>(
                    pvp + (size_t)(cb + cs * 32 + lo5) * N_ + m0 + ms * 16 + hi1 * 8);
        const int mnext = (it < 63) ? (m0 + 64) : 0;
        bf16x8 kn[4];
#pragma unroll
        for (int kk = 0; kk < 4; ++kk)
            kn[kk] = *reinterpret_cast<const bf16x8*>(
                kp + (size_t)(mnext + msel * 16 + lo) * CQD + kk * 32 + hi * 8);

        // ---- E' phase: D'[m-local 16][n 32] = K x Q, K pre-loaded ----
        f32x4 e[2];
#pragma unroll
        for (int nb = 0; nb < 2; ++nb) e[nb] = (f32x4){0.f, 0.f, 0.f, 0.f};
#pragma unroll
        for (int kk = 0; kk < 4; ++kk)
#pragma unroll
            for (int nb = 0; nb < 2; ++nb)
                e[nb] = mfma16(kc[kk], qf[nb][kk], e[nb]);

        // exp -> rowsum + packed swizzled p write (rows n, cols m-local 64)
        unsigned char* pb = p_lds[it & 1];
#pragma unroll
        for (int nb = 0; nb < 2; ++nb) {
            const int row  = nh * 32 + nb * 16 + lo;
            const int cswz = (((msel * 2 + (hi >> 1)) ^ (row & 7)) << 4) + (hi & 1) * 8;
#pragma unroll
            for (int s = 0; s < 2; ++s) {
                const float p0 = __expf(e[nb][2 * s]);
                const float p1 = __expf(e[nb][2 * s + 1]);
                rs[nb] += p0 + p1;
                const unsigned int pk = ((unsigned int)f2bf(p1) << 16) | f2bf(p0);
                *reinterpret_cast<unsigned int*>(pb + row * 128 + cswz + s * 4) = pk;
            }
        }
        __syncthreads();   // p ready; also drains Bf/kn loads (vmcnt0)

        // ---- PV phase: pure compute. D[n 0..63][c 0..63] += p @ PV^T ----
#pragma unroll
        for (int ms = 0; ms < 4; ++ms) {
            bf16x8 pa[2];
#pragma unroll
            for (int nb = 0; nb < 2; ++nb) {
                const int row = nb * 32 + lo5;
                pa[nb] = *reinterpret_cast<const bf16x8*>(
                    pb + row * 128 + (((ms * 2 + hi1) ^ (row & 7)) << 4));
            }
#pragma unroll
            for (int nb = 0; nb < 2; ++nb)
#pragma unroll
                for (int cs = 0; cs < 2; ++cs)
                    acc[nb][cs] = mfma32(pa[nb], Bf[ms][cs], acc[nb][cs]);
        }
#pragma unroll
        for (int kk = 0; kk < 4; ++kk) kc[kk] = kn[kk];
    }

    // ---- rowsum: reduce across hi groups (m), accumulate across msel waves ----
#pragma unroll
    for (int nb = 0; nb < 2; ++nb) {
        float v = rs[nb];
        v += __shfl_xor(v, 16);
        v += __shfl_xor(v, 32);
        rs[nb] = v;
    }
    if (l < 16) {
        atomicAdd(&red[nh * 32 + l],      rs[0]);
        atomicAdd(&red[nh * 32 + 16 + l], rs[1]);
    }
    __syncthreads();

    // ---- epilogue: out = gamma * O / rowsum + x3d ----
    const float gmv  = gamma_p[0];
    const float* x3p = x3d + (size_t)b * 64 * 65536;
    float*       op  = outp + (size_t)b * 64 * 65536;
#pragma unroll
    for (int nb = 0; nb < 2; ++nb) {
#pragma unroll
        for (int j = 0; j < 16; ++j) {
            const int   nl   = nb * 32 + hi1 * 4 + (j & 3) + ((j >> 2) * 8);
            const float rinv = 1.0f / red[nl];
            const int   nn   = n0 + nl;
#pragma unroll
            for (int cs = 0; cs < 2; ++cs) {
                const int    cp  = cb + cs * 32 + lo5;
                const size_t idx = (size_t)(cp >> 4) * 65536 + (size_t)nn * 16 + (cp & 15);
                op[idx] = gmv * acc[nb][cs][j] * rinv + x3p[idx];
            }
        }
    }
}

extern "C" void kernel_launch(void* const* d_in, const int* in_sizes, int n_in,
                              void* d_out, int out_size, void* d_ws, size_t ws_size,
                              hipStream_t stream)
{
    const float* x2d = (const float*)d_in[0];
    const float* x3d = (const float*)d_in[1];
    const float* Wq  = (const float*)d_in[2];
    const float* bq  = (const float*)d_in[3];
    const float* Wk  = (const float*)d_in[4];
    const float* bk  = (const float*)d_in[5];
    const float* Wv  = (const float*)d_in[6];
    const float* bv  = (const float*)d_in[7];
    const float* gm  = (const float*)d_in[8];

    char* ws = (char*)d_ws;
    unsigned short* Qb = (unsigned short*)ws;                    // 2 MiB
    unsigned short* Kb = (unsigned short*)(ws + (2u << 20));     // 2 MiB
    unsigned short* PV = (unsigned short*)(ws + (4u << 20));     // 16 MiB

    proj_kernel<<<512, 256, 0, stream>>>(x2d, Wq, bq, Wk, bk, Wv, bv, Qb, Kb, PV);
    attn_kernel<<<256, 512, 0, stream>>>(Qb, Kb, PV, x3d, gm, (float*)d_out);
}

// Round 6
// 329.473 us; speedup vs baseline: 1.0198x; 1.0198x over previous
//
#include <hip/hip_runtime.h>
#include <hip/hip_bf16.h>

typedef __attribute__((ext_vector_type(8)))  __bf16 bf16x8;
typedef __attribute__((ext_vector_type(4)))  float  f32x4;
typedef __attribute__((ext_vector_type(16))) float  f32x16;

#define N_ 4096

static __device__ __forceinline__ unsigned short f2bf(float f) {
    union { float f; unsigned int u; } cv; cv.f = f;
    unsigned int u = cv.u;
    u += 0x7fffu + ((u >> 16) & 1u);   // RNE
    return (unsigned short)(u >> 16);
}
static __device__ __forceinline__ f32x4 mfma16(bf16x8 a, bf16x8 b, f32x4 c) {
    return __builtin_amdgcn_mfma_f32_16x16x32_bf16(a, b, c, 0, 0, 0);
}
static __device__ __forceinline__ f32x16 mfma32(bf16x8 a, bf16x8 b, f32x16 c) {
    return __builtin_amdgcn_mfma_f32_32x32x16_bf16(a, b, c, 0, 0, 0);
}

// ---------------------------------------------------------------------------
// Workspace layouts (all bf16 as unsigned short):
//  Qb [b][n 4096][c' 128]                              (2 MiB)  row = 256B
//  KF [b][mt 128][mq 2][kk 4][hi 4][lo 16]x8           (2 MiB)  frag-units:
//      unit(mt,mq,kk,hi,lo) = K[m=mt*32+mq*16+lo][c' kk*32+hi*8 ..+8)
//  PVF[b][mt 128][cblk 32][ks 2][hi1 2][lo5 32]x8      (16 MiB) frag-units:
//      unit = PV[c'=cblk*32+lo5][m = mt*32+ks*16+hi1*8 ..+8)
// ---------------------------------------------------------------------------

// proj: grid 512 (2 b x 256 col-tiles of 256), block 256.
// thread col = tile*256+t -> (m = col>>4, dd = col&15). xr[64] in regs,
// W via wave-uniform scalar loads. Outputs bounced through LDS so every
// global store is full-line contiguous.
__global__ __launch_bounds__(256) void proj_kernel(
    const float* __restrict__ x2d,
    const float* __restrict__ Wq, const float* __restrict__ bq,
    const float* __restrict__ Wk, const float* __restrict__ bk,
    const float* __restrict__ Wv, const float* __restrict__ bv,
    unsigned short* __restrict__ Qb, unsigned short* __restrict__ KF,
    unsigned short* __restrict__ PVF)
{
    __shared__ unsigned short vlds[1024][16];   // [c'][m-local 16] 32 KB
    __shared__ unsigned short qlds[16][128];    // [n-local][c'q]   4 KB
    __shared__ unsigned short klds[16][128];    // [m-local][c'k]   4 KB

    const int t    = threadIdx.x;
    const int blk  = blockIdx.x;
    const int b    = blk >> 8;
    const int tile = blk & 255;
    const int col  = (tile << 8) + t;
    const int dd   = col & 15;
    const int ml   = (col >> 4) & 15;   // m within the block's 16
    const int mt   = tile >> 1;
    const int mq   = tile & 1;

    const float* xb = x2d + (size_t)b * 64 * 65536 + col;
    float xr[64];
#pragma unroll
    for (int c = 0; c < 64; ++c) xr[c] = xb[(size_t)c * 65536];

    // ---- Q + K (8 rows each) ----
    {
        float aq[8], ak[8];
#pragma unroll
        for (int j = 0; j < 8; ++j) { aq[j] = bq[j]; ak[j] = bk[j]; }
#pragma unroll 8
        for (int c = 0; c < 64; ++c) {
            const float xv = xr[c];
#pragma unroll
            for (int j = 0; j < 8; ++j) {
                aq[j] += Wq[j * 64 + c] * xv;
                ak[j] += Wk[j * 64 + c] * xv;
            }
        }
#pragma unroll
        for (int j = 0; j < 8; ++j) {
            qlds[ml][j * 16 + dd] = f2bf(aq[j]);
            klds[ml][j * 16 + dd] = f2bf(ak[j]);
        }
    }
    // ---- V (64 rows, chunks of 4) ----
#pragma unroll 1
    for (int jc = 0; jc < 16; ++jc) {
        float av[4];
#pragma unroll
        for (int jj = 0; jj < 4; ++jj) av[jj] = bv[jc * 4 + jj];
#pragma unroll 8
        for (int c = 0; c < 64; ++c) {
            const float xv = xr[c];
#pragma unroll
            for (int jj = 0; jj < 4; ++jj) av[jj] += Wv[(jc * 4 + jj) * 64 + c] * xv;
        }
#pragma unroll
        for (int jj = 0; jj < 4; ++jj)
            vlds[(jc * 4 + jj) * 16 + dd][ml] = f2bf(av[jj]);
    }
    __syncthreads();

    // ---- coalesced writeout ----
    // Q: 16 rows x 256B = 4 KB contiguous
    {
        const int row = t >> 4, slot = t & 15;
        const uint4 qv = *reinterpret_cast<const uint4*>(&qlds[row][slot << 3]);
        unsigned short* qd = Qb + (size_t)b * 524288 + ((size_t)((tile << 4) + row) << 7) + (slot << 3);
        *reinterpret_cast<uint4*>(qd) = qv;
    }
    // K -> KF frag-units: unit t = (kk,hi,lo)
    {
        const int kk = t >> 6, hh = (t >> 4) & 3, ll = t & 15;
        const uint4 kv = *reinterpret_cast<const uint4*>(&klds[ll][(kk << 5) + (hh << 3)]);
        unsigned short* kd = KF + (size_t)b * 524288 + ((size_t)(mt << 1) + mq) * 2048 + (t << 3);
        *reinterpret_cast<uint4*>(kd) = kv;
    }
    // V -> PVF frag-units (this block's ks = mq half): 8 units/thread
    {
        unsigned short* pvt = PVF + (size_t)b * 4194304 + (size_t)mt * 32768;
        const int cblk = t >> 3;
        const int hi1  = (t >> 2) & 1;
#pragma unroll
        for (int j = 0; j < 8; ++j) {
            const int lo5 = ((t & 3) << 3) + j;
            const uint4 vv = *reinterpret_cast<const uint4*>(&vlds[(cblk << 5) + lo5][hi1 << 3]);
            *reinterpret_cast<uint4*>(&pvt[(cblk << 10) + (mq << 9) + (hi1 << 8) + (lo5 << 3)]) = vv;
        }
    }
}

// ---------------------------------------------------------------------------
// attn: grid 512, id&7 = (b,cq) [XCD-pinned], id>>3 = n-tile (64 n).
// 8 waves/512 thr, 2 blocks/CU.
// Wave roles: E'-tile (mq=w>>2, ng=w&3); PV-tile (nh=w&1, cg=w>>1).
// Per m-step-32 iter: syncthreads (drains prev prefetch) -> issue gll PV[nxt]
// + K-frag loads[nxt] -> E' (4 mfma16, K regs) -> exp -> p frag-units to LDS
// -> raw barrier (lgkm only, prefetch stays in flight) -> PV (4 mfma32, all
// conflict-free LDS reads). Unnormalized acc + rowsum; epilogue divides.
// ---------------------------------------------------------------------------
__global__ __launch_bounds__(512, 4) void attn_kernel(
    const unsigned short* __restrict__ Qb, const unsigned short* __restrict__ KF,
    const unsigned short* __restrict__ PVF,
    const float* __restrict__ x3d, const float* __restrict__ gamma_p,
    float* __restrict__ outp)
{
    __shared__ __align__(16) unsigned short pvlds[2][8192]; // 2 x 16 KB PV tile
    __shared__ __align__(16) unsigned short plds[2048];     // 4 KB p tile
    __shared__ float red[64];

    const int t   = threadIdx.x;
    const int w   = t >> 6;
    const int l   = t & 63;
    const int lo  = l & 15;
    const int hi  = l >> 4;
    const int l8  = l << 3;

    const int id    = blockIdx.x;
    const int combo = id & 7;
    const int b     = combo >> 2;
    const int cq    = combo & 3;
    const int n0    = (id >> 3) << 6;
    const int mq    = w >> 2;      // E' m-half
    const int ng    = w & 3;       // E' n-16-group
    const int nh    = w & 1;       // PV n-half
    const int cg    = w >> 1;      // PV c-64-group (0..3)

    const unsigned short* qp   = Qb  + (size_t)b * 524288;
    const unsigned short* kfp  = KF  + (size_t)b * 524288;
    const unsigned short* pvfp = PVF + (size_t)b * 4194304;

    // Q B-frags (held whole kernel)
    bf16x8 qf[4];
#pragma unroll
    for (int kk = 0; kk < 4; ++kk)
        qf[kk] = *reinterpret_cast<const bf16x8*>(
            qp + ((size_t)(n0 + ng * 16 + lo) << 7) + (kk << 5) + (hi << 3));

    // prologue: K frags + PV tile for mt=0
    bf16x8 kc[4], kcn[4];
#pragma unroll
    for (int kk = 0; kk < 4; ++kk)
        kc[kk] = *reinterpret_cast<const bf16x8*>(kfp + (size_t)mq * 2048 + (kk << 9) + l8);
#pragma unroll
    for (int r2 = 0; r2 < 2; ++r2) {
        const int round = (w << 1) + r2;
        __builtin_amdgcn_global_load_lds(
            (const __attribute__((address_space(1))) void*)(pvfp + (cq << 13) + (round << 9) + l8),
            (__attribute__((address_space(3))) void*)(&pvlds[0][round << 9]),
            16, 0, 0);
    }

    f32x16 acc[2];
#pragma unroll
    for (int cs = 0; cs < 2; ++cs)
#pragma unroll
        for (int r = 0; r < 16; ++r) acc[cs][r] = 0.f;
    float rs = 0.f;
    if (t < 64) red[t] = 0.f;

    for (int it = 0; it < 128; ++it) {
        const int cur = it & 1;
        __syncthreads();   // (a): prefetches landed; prev p-reads done

        // ---- issue next-iter prefetch (in flight across both phases) ----
        const int mtn = (it < 127) ? it + 1 : 127;
        const unsigned short* srcb = pvfp + (size_t)mtn * 32768 + (cq << 13);
#pragma unroll
        for (int r2 = 0; r2 < 2; ++r2) {
            const int round = (w << 1) + r2;
            __builtin_amdgcn_global_load_lds(
                (const __attribute__((address_space(1))) void*)(srcb + (round << 9) + l8),
                (__attribute__((address_space(3))) void*)(&pvlds[cur ^ 1][round << 9]),
                16, 0, 0);
        }
        const unsigned short* kfb = kfp + ((size_t)(mtn << 1) + mq) * 2048;
#pragma unroll
        for (int kk = 0; kk < 4; ++kk)
            kcn[kk] = *reinterpret_cast<const bf16x8*>(kfb + (kk << 9) + l8);

        // ---- E' phase: pure register compute ----
        f32x4 e = (f32x4){0.f, 0.f, 0.f, 0.f};
#pragma unroll
        for (int kk = 0; kk < 4; ++kk) e = mfma16(kc[kk], qf[kk], e);

        const float p0 = __expf(e[0]), p1 = __expf(e[1]);
        const float p2 = __expf(e[2]), p3 = __expf(e[3]);
        rs += (p0 + p1) + (p2 + p3);
        const unsigned int w0 = ((unsigned int)f2bf(p1) << 16) | f2bf(p0);
        const unsigned int w1 = ((unsigned int)f2bf(p3) << 16) | f2bf(p2);
        const int u = ((ng >> 1) << 7) + (mq << 6) + ((hi >> 1) << 5) + ((ng & 1) << 4) + lo;
        *reinterpret_cast<uint2*>(&plds[(u << 3) + ((hi & 1) << 2)]) = make_uint2(w0, w1);

        // ---- (b): raw barrier, LDS-drain only (vmem prefetch stays live) ----
        asm volatile("s_waitcnt lgkmcnt(0)" ::: "memory");
        __builtin_amdgcn_sched_barrier(0);
        __builtin_amdgcn_s_barrier();
        __builtin_amdgcn_sched_barrier(0);

        // ---- PV phase: conflict-free LDS reads + 4 mfma32 ----
        const unsigned short* pvc = &pvlds[cur][0];
#pragma unroll
        for (int ks = 0; ks < 2; ++ks) {
            const bf16x8 pa = *reinterpret_cast<const bf16x8*>(&plds[(nh << 10) + (ks << 9) + l8]);
#pragma unroll
            for (int cs = 0; cs < 2; ++cs) {
                const int cblk = (cg << 1) + cs;
                const bf16x8 Bf = *reinterpret_cast<const bf16x8*>(&pvc[(cblk << 10) + (ks << 9) + l8]);
                acc[cs] = mfma32(pa, Bf, acc[cs]);
            }
        }
#pragma unroll
        for (int kk = 0; kk < 4; ++kk) kc[kk] = kcn[kk];
    }

    // ---- rowsum: sum over hi-groups, accumulate mq-halves in LDS ----
    {
        float v = rs;
        v += __shfl_xor(v, 16);
        v += __shfl_xor(v, 32);
        if (l < 16) atomicAdd(&red[ng * 16 + l], v);
    }
    __syncthreads();

    // ---- epilogue: out = gamma * O / rowsum + x3d (full-line stores) ----
    const float gmv  = gamma_p[0];
    const int   lo5  = l & 31;
    const int   hi1  = l >> 5;
    const float* x3p = x3d + (size_t)b * 64 * 65536;
    float*       op  = outp + (size_t)b * 64 * 65536;
#pragma unroll
    for (int cs = 0; cs < 2; ++cs) {
        const int    cp   = cq * 256 + cg * 64 + cs * 32 + lo5;
        const size_t base = (size_t)(cp >> 4) * 65536 + (size_t)(cp & 15);
#pragma unroll
        for (int j = 0; j < 16; ++j) {
            const int   nl   = nh * 32 + (j & 3) + ((j >> 2) << 3) + (hi1 << 2);
            const float rinv = 1.0f / red[nl];
            const size_t idx = base + (size_t)(n0 + nl) * 16;
            op[idx] = gmv * acc[cs][j] * rinv + x3p[idx];
        }
    }
}

extern "C" void kernel_launch(void* const* d_in, const int* in_sizes, int n_in,
                              void* d_out, int out_size, void* d_ws, size_t ws_size,
                              hipStream_t stream)
{
    const float* x2d = (const float*)d_in[0];
    const float* x3d = (const float*)d_in[1];
    const float* Wq  = (const float*)d_in[2];
    const float* bq  = (const float*)d_in[3];
    const float* Wk  = (const float*)d_in[4];
    const float* bk  = (const float*)d_in[5];
    const float* Wv  = (const float*)d_in[6];
    const float* bv  = (const float*)d_in[7];
    const float* gm  = (const float*)d_in[8];

    char* ws = (char*)d_ws;
    unsigned short* Qb  = (unsigned short*)ws;                  // 2 MiB
    unsigned short* KF  = (unsigned short*)(ws + (2u << 20));   // 2 MiB
    unsigned short* PVF = (unsigned short*)(ws + (4u << 20));   // 16 MiB

    proj_kernel<<<512, 256, 0, stream>>>(x2d, Wq, bq, Wk, bk, Wv, bv, Qb, KF, PVF);
    attn_kernel<<<512, 512, 0, stream>>>(Qb, KF, PVF, x3d, gm, (float*)d_out);
}